// Round 8
// baseline (331.785 us; speedup 1.0000x reference)
//
#include <hip/hip_runtime.h>
#include <hip/hip_bf16.h>

typedef unsigned short u16;
typedef unsigned int u32;
typedef unsigned long long u64;

__device__ __forceinline__ float bf2f(u16 h) {
    return __uint_as_float(((u32)h) << 16);
}
__device__ __forceinline__ u16 f2bf(float f) {
    __hip_bfloat16 h = __float2bfloat16(f);   // RNE
    return *reinterpret_cast<u16*>(&h);
}

// ---------------- build-side (multi-kernel, proven R0 code) ----------------
#define BKT_SHIFT 7
#define BKT_SIZE  128
#define CHUNK     2048

// ---------------- compute-side persistent kernel ----------------
#define CGRID     1536         // 256 CU x 6 blocks/CU (25.6KB LDS, VGPR<=85)
#define SPMM_ROWS 32
#define SPMM_LDSE 2048
// smem: As[32*132]f @0 (16896B) | Bs[32*64]f @16896 (8192B) | sums[128]f @25088 (512B)
#define CLDS      25600
#define BAR_GROUPS 48
#define BAR_GSIZE  32          // 48*32 = 1536
#define NXCD      8

// ---------- MALL-direct accessors: BARRIER WORDS ONLY ----------
// R7 lesson: MALL-direct (agent-relaxed) data stores are write-through with no
// cross-lane combining -> ~16B-granule transaction per 4-8B store, 3x write
// amplification (WRITE_SIZE 93MB vs 34MB ideal). Plane data now uses normal
// write-back cached stores; coherence is provided by one wbl2 per XCD at each
// barrier (below). Only barrier counters stay MALL-direct.
__device__ __forceinline__ void sti(int* p, int v) {
    __hip_atomic_store(p, v, __ATOMIC_RELAXED, __HIP_MEMORY_SCOPE_AGENT);
}
__device__ __forceinline__ int ldi(const int* p) {
    return __hip_atomic_load((int*)p, __ATOMIC_RELAXED, __HIP_MEMORY_SCOPE_AGENT);
}
__device__ __forceinline__ int aadd(int* p) {
    return __hip_atomic_fetch_add(p, 1, __ATOMIC_RELAXED, __HIP_MEMORY_SCOPE_AGENT);
}
__device__ __forceinline__ float lo16f(u32 w) { return __uint_as_float(w << 16); }
__device__ __forceinline__ float hi16f(u32 w) { return __uint_as_float(w & 0xffff0000u); }
__device__ __forceinline__ u32 packbf(float a, float b) {
    return (u32)f2bf(a) | ((u32)f2bf(b) << 16);
}

// ==================== CSR build kernels (R0, zero global atomics) ====================
__global__ __launch_bounds__(256) void hist_kernel(const int* __restrict__ dst,
                                                   int* __restrict__ hist,
                                                   int E, int nbA, int nbuck) {
    __shared__ int lh[512];
    for (int j = threadIdx.x; j < nbuck; j += 256) lh[j] = 0;
    __syncthreads();
    int base = blockIdx.x * CHUNK;
    int end  = min(E, base + CHUNK);
    for (int e = base + threadIdx.x; e < end; e += 256)
        atomicAdd(&lh[dst[e] >> BKT_SHIFT], 1);
    __syncthreads();
    for (int j = threadIdx.x; j < nbuck; j += 256)
        hist[j * nbA + blockIdx.x] = lh[j];       // bin-major for the scan
}
__global__ __launch_bounds__(256) void scanA_kernel(const int* __restrict__ in,
                                                    int* __restrict__ outp1,
                                                    int* __restrict__ bsum, int n) {
    __shared__ int lds[256];
    int i = blockIdx.x * 256 + threadIdx.x;
    int v = (i < n) ? in[i] : 0;
    lds[threadIdx.x] = v;
    __syncthreads();
    #pragma unroll
    for (int off = 1; off < 256; off <<= 1) {
        int t = (threadIdx.x >= off) ? lds[threadIdx.x - off] : 0;
        __syncthreads();
        lds[threadIdx.x] += t;
        __syncthreads();
    }
    if (i < n) outp1[i + 1] = lds[threadIdx.x];
    if (threadIdx.x == 255) bsum[blockIdx.x] = lds[255];
}
__global__ __launch_bounds__(1024) void scanB_kernel(int* __restrict__ bsum, int nb) {
    __shared__ int lds[1024];
    int t = threadIdx.x;
    int v = (t < nb) ? bsum[t] : 0;
    lds[t] = v;
    __syncthreads();
    #pragma unroll
    for (int off = 1; off < 1024; off <<= 1) {
        int u = (t >= off) ? lds[t - off] : 0;
        __syncthreads();
        lds[t] += u;
        __syncthreads();
    }
    if (t < nb) bsum[t] = lds[t] - v;
}
__global__ __launch_bounds__(256) void scanC_kernel(int* __restrict__ outp1,
                                                    const int* __restrict__ bsum, int n) {
    int i = blockIdx.x * 256 + threadIdx.x;
    if (i < n) outp1[i + 1] += bsum[blockIdx.x];
    if (i == 0) outp1[0] = 0;
}
__global__ __launch_bounds__(256) void bucket_scatter_kernel(
    const int* __restrict__ src, const int* __restrict__ dst,
    const int* __restrict__ hofs, int2* __restrict__ bucketed,
    int E, int nbA, int nbuck)
{
    __shared__ int lbase[512];
    __shared__ int lcnt[512];
    for (int j = threadIdx.x; j < nbuck; j += 256) {
        lbase[j] = hofs[j * nbA + blockIdx.x];
        lcnt[j] = 0;
    }
    __syncthreads();
    int base = blockIdx.x * CHUNK;
    int end  = min(E, base + CHUNK);
    for (int e = base + threadIdx.x; e < end; e += 256) {
        int d = dst[e];
        int b = d >> BKT_SHIFT;
        int r = atomicAdd(&lcnt[b], 1);
        bucketed[lbase[b] + r] = make_int2(src[e], d);
    }
}
__global__ __launch_bounds__(256) void csr_finalize_kernel(
    const int2* __restrict__ bucketed, const int* __restrict__ hofs,
    int* __restrict__ rowptr, float* __restrict__ dis,
    u32* __restrict__ ecol, int E, int nbA, int nbuck, int n)
{
    __shared__ int cnt[BKT_SIZE];
    __shared__ int run[BKT_SIZE];
    int b = blockIdx.x;
    int bstart = hofs[b * nbA];
    int bend   = (b == nbuck - 1) ? E : hofs[(b + 1) * nbA];
    for (int j = threadIdx.x; j < BKT_SIZE; j += 256) cnt[j] = 0;
    __syncthreads();
    for (int i = bstart + threadIdx.x; i < bend; i += 256)
        atomicAdd(&cnt[bucketed[i].y & (BKT_SIZE - 1)], 1);
    __syncthreads();
    if (threadIdx.x == 0) {
        int runacc = 0;
        for (int j = 0; j < BKT_SIZE; ++j) {
            int c = cnt[j];
            run[j] = runacc;
            runacc += c;
        }
    }
    __syncthreads();
    for (int j = threadIdx.x; j < BKT_SIZE; j += 256) {
        int d = b * BKT_SIZE + j;
        if (d < n) {
            rowptr[d] = bstart + run[j];
            int c = cnt[j];
            dis[d] = (c > 0) ? rsqrtf((float)c) : 0.0f;
        }
    }
    if (b == 0 && threadIdx.x == 0) rowptr[n] = E;
    __syncthreads();
    for (int i = bstart + threadIdx.x; i < bend; i += 256) {
        int2 p = bucketed[i];
        int j = p.y & (BKT_SIZE - 1);
        int r = atomicAdd(&run[j], 1);
        ecol[bstart + r] = (u32)p.x;
    }
}

// ==================== compute-side persistent kernel ====================

// ---- device barrier with per-XCD L2 writeback ----
// Phase 1: hierarchical arrival (all stores are in each block's local L2 after
//   __syncthreads). Phase 2: exactly ONE block per XCD (CAS-claimed; XCD id via
//   s_getreg(HW_REG_XCC_ID) [measured m09]) issues a release fence ->
//   buffer_wbl2 flushes that XCD's dirty lines to the MALL; post-counter
//   reaches 8 -> everyone proceeds. Reads need NO invalidate: the plane plan
//   is single-assignment (each plane written once, read only after; no XCD can
//   hold a stale clean line of an address it reads).
__device__ __forceinline__ void grid_bar(int* barr, int epoch) {
    __syncthreads();                 // drains vmem: this block's stores in L2
    if (threadIdx.x == 0) {
        const int g = (int)blockIdx.x % BAR_GROUPS;
        int old = aadd(barr + g * 16);
        if (old == epoch * BAR_GSIZE - 1) {          // last of group
            int r = aadd(barr + 768);
            if (r == epoch * BAR_GROUPS - 1)         // last group
                sti(barr + 784, epoch);              // pre-release
        }
        while (ldi(barr + 784) < epoch)
            __builtin_amdgcn_s_sleep(4);
        // all blocks' stores are now resident in their XCDs' L2s
        unsigned xcd;
        asm volatile("s_getreg_b32 %0, hwreg(HW_REG_XCC_ID)" : "=s"(xcd));
        int expected = epoch - 1;
        if (__hip_atomic_compare_exchange_strong(
                barr + 832 + (int)xcd * 16, &expected, epoch,
                __ATOMIC_RELAXED, __ATOMIC_RELAXED, __HIP_MEMORY_SCOPE_AGENT)) {
            __builtin_amdgcn_fence(__ATOMIC_RELEASE, "agent");  // buffer_wbl2
            aadd(barr + 800);                                    // post
        }
        while (ldi(barr + 800) < epoch * NXCD)
            __builtin_amdgcn_s_sleep(4);
    }
    __syncthreads();
}

// ---- GEMM1, K-chunked (4 x 32); plane writes = plain cached u64 stores ----
__device__ void gemm1_phase(char* smem, const float* __restrict__ x,
                            const float* __restrict__ W1,
                            const float* __restrict__ dis,
                            u16* __restrict__ zb, int n, int nstride)
{
    float* As   = (float*)smem;              // [32][132]
    float* Bs   = (float*)(smem + 16896);    // [32][64]
    float* sums = (float*)(smem + 25088);    // [128]
    const int t  = threadIdx.x;
    const int tx = t & 15;
    const int ty = t >> 4;
    const int c  = t & 15;
    const int g  = t >> 4;
    const int ntiles = (n + 127) >> 7;
    for (int tile = blockIdx.x; tile < ntiles; tile += CGRID) {
        const int block_row = tile << 7;
        float acc[8][4];
        #pragma unroll
        for (int i = 0; i < 8; ++i)
            #pragma unroll
            for (int j = 0; j < 4; ++j) acc[i][j] = 0.f;

        for (int kc = 0; kc < 4; ++kc) {
            #pragma unroll
            for (int i = 0; i < 8; ++i) {
                int row  = g + 16 * i;
                int grow = block_row + row;
                float v0 = 0.f, v1 = 0.f;
                if (grow < n) {
                    const float* xp = x + (long)grow * 128 + kc * 32 + c;
                    v0 = xp[0]; v1 = xp[16];
                }
                As[(c +  0) * 132 + row] = v0;
                As[(c + 16) * 132 + row] = v1;
                float red = v0 + v1;
                #pragma unroll
                for (int off = 8; off > 0; off >>= 1) red += __shfl_down(red, off, 16);
                if (c == 0) { if (kc == 0) sums[row] = red; else sums[row] += red; }
            }
            #pragma unroll
            for (int i2 = 0; i2 < 2; ++i2) {
                int kk = g + 16 * i2;
                int kglob = kc * 32 + kk;
                float4 wv = *(const float4*)(W1 + (c >> 2) * 2048 + kglob * 16 + 4 * (c & 3));
                *(float4*)(Bs + kk * 64 + 4 * c) = wv;
            }
            __syncthreads();
            #pragma unroll 4
            for (int kk = 0; kk < 32; ++kk) {
                float4 a0 = *(const float4*)(As + kk * 132 + 8 * ty);
                float4 a1 = *(const float4*)(As + kk * 132 + 8 * ty + 4);
                float4 bv = *(const float4*)(Bs + kk * 64 + 4 * tx);
                float ar[8] = {a0.x, a0.y, a0.z, a0.w, a1.x, a1.y, a1.z, a1.w};
                float br[4] = {bv.x, bv.y, bv.z, bv.w};
                #pragma unroll
                for (int i = 0; i < 8; ++i)
                    #pragma unroll
                    for (int j = 0; j < 4; ++j)
                        acc[i][j] += ar[i] * br[j];
            }
            __syncthreads();
        }
        int plane = tx >> 2;
        int oo4   = 4 * (tx & 3);
        #pragma unroll
        for (int i = 0; i < 8; ++i) {
            int row  = 8 * ty + i;
            int grow = block_row + row;
            if (grow < n) {
                float s = 1.0f / fmaxf(sums[row], 1e-8f);
                if (plane != 0) s *= dis[grow];          // tilde space for SpMM inputs
                u64* zp = (u64*)zb + (size_t)plane * (nstride >> 2) + (size_t)grow * 4 + (oo4 >> 2);
                *zp = (u64)packbf(acc[i][0] * s, acc[i][1] * s)
                    | ((u64)packbf(acc[i][2] * s, acc[i][3] * s) << 32);
            }
        }
        __syncthreads();
    }
}

// ---- CSR SpMM (tilde form), 32 rows x 8 lanes, unroll 8 ----
// All loads and stores plain cached; row groups are 1KB-aligned so no L2 line
// is ever written by two blocks (safe under write-back).
__device__ void spmm_phase(char* smem,
    const u16* __restrict__ in, const u16* __restrict__ addsrc,
    u16* __restrict__ out1, u16* __restrict__ out2,
    const int* __restrict__ rowptr, const u32* __restrict__ ecol,
    const float* __restrict__ dis, const float* __restrict__ b,
    int relu, int sq1, int n)
{
    u32* eld = (u32*)smem;
    const u32* inw = (const u32*)in;     // plane row = 8 u32 (16 bf16)
    const int ngroups = (n + SPMM_ROWS - 1) / SPMM_ROWS;
    const int lr = threadIdx.x >> 3;
    const int q  = threadIdx.x & 7;
    for (int g = blockIdx.x; g < ngroups; g += CGRID) {
        const int r0 = g * SPMM_ROWS;
        const int rend = min(n, r0 + SPMM_ROWS);
        const int estart = rowptr[r0];
        const int eendb  = rowptr[rend];
        const int ne = eendb - estart;
        const bool lds_ok = (ne <= SPMM_LDSE);
        if (lds_ok) {
            for (int j = threadIdx.x; j < ne; j += 256)
                eld[j] = ecol[estart + j];
        }
        __syncthreads();
        const int r = r0 + lr;
        if (r < n) {
            int e0 = rowptr[r], e1 = rowptr[r + 1];
            float ax0=0,ay0=0, ax1=0,ay1=0, ax2=0,ay2=0, ax3=0,ay3=0;
            if (lds_ok) {
                int le = e0 - estart, le1 = e1 - estart;
                for (; le + 8 <= le1; le += 8) {
                    u32 s0 = eld[le+0], s1 = eld[le+1], s2 = eld[le+2], s3 = eld[le+3];
                    u32 s4 = eld[le+4], s5 = eld[le+5], s6 = eld[le+6], s7 = eld[le+7];
                    u32 w0 = inw[(size_t)s0 * 8 + q];
                    u32 w1 = inw[(size_t)s1 * 8 + q];
                    u32 w2 = inw[(size_t)s2 * 8 + q];
                    u32 w3 = inw[(size_t)s3 * 8 + q];
                    u32 w4 = inw[(size_t)s4 * 8 + q];
                    u32 w5 = inw[(size_t)s5 * 8 + q];
                    u32 w6 = inw[(size_t)s6 * 8 + q];
                    u32 w7 = inw[(size_t)s7 * 8 + q];
                    ax0 += lo16f(w0); ay0 += hi16f(w0);
                    ax1 += lo16f(w1); ay1 += hi16f(w1);
                    ax2 += lo16f(w2); ay2 += hi16f(w2);
                    ax3 += lo16f(w3); ay3 += hi16f(w3);
                    ax0 += lo16f(w4); ay0 += hi16f(w4);
                    ax1 += lo16f(w5); ay1 += hi16f(w5);
                    ax2 += lo16f(w6); ay2 += hi16f(w6);
                    ax3 += lo16f(w7); ay3 += hi16f(w7);
                }
                for (; le < le1; ++le) {
                    u32 w0 = inw[(size_t)eld[le] * 8 + q];
                    ax0 += lo16f(w0); ay0 += hi16f(w0);
                }
            } else {
                int e = e0;
                for (; e + 4 <= e1; e += 4) {
                    u32 s0 = ecol[e], s1 = ecol[e+1], s2 = ecol[e+2], s3 = ecol[e+3];
                    u32 w0 = inw[(size_t)s0 * 8 + q];
                    u32 w1 = inw[(size_t)s1 * 8 + q];
                    u32 w2 = inw[(size_t)s2 * 8 + q];
                    u32 w3 = inw[(size_t)s3 * 8 + q];
                    ax0 += lo16f(w0); ay0 += hi16f(w0);
                    ax1 += lo16f(w1); ay1 += hi16f(w1);
                    ax2 += lo16f(w2); ay2 += hi16f(w2);
                    ax3 += lo16f(w3); ay3 += hi16f(w3);
                }
                for (; e < e1; ++e) {
                    u32 w0 = inw[(size_t)ecol[e] * 8 + q];
                    ax0 += lo16f(w0); ay0 += hi16f(w0);
                }
            }
            float Sx = (ax0 + ax1) + (ax2 + ax3);
            float Sy = (ay0 + ay1) + (ay2 + ay3);
            float d1 = dis[r];
            float sc1 = sq1 ? d1 * d1 : d1;
            float Ax = Sx * sc1, Ay = Sy * sc1;
            if (addsrc) {
                u32 s = ((const u32*)addsrc)[(size_t)r * 8 + q];
                Ax += lo16f(s); Ay += hi16f(s);
            }
            if (b) {
                Ax += b[2 * q];
                Ay += b[2 * q + 1];
            }
            if (relu) {
                Ax = fmaxf(Ax, 0.f);
                Ay = fmaxf(Ay, 0.f);
            }
            ((u32*)out1)[(size_t)r * 8 + q] = packbf(Ax, Ay);
            if (out2)
                ((u32*)out2)[(size_t)r * 8 + q] = packbf(Ax * d1, Ay * d1);
        }
        __syncthreads();   // WAR: protect eld before next group restage
    }
}

// ---- GEMM2, K-chunked (2 x 32 = 2 planes/chunk); plain cached reads ----
// Input planes H,G1,G2,G3 (indices 6,8,10,12) are fresh (never read before
// gemm2), so cached reads are safe with no invalidate.
__device__ void gemm2_phase(char* smem, const u16* __restrict__ zb,
                            const float* __restrict__ W2,
                            const float* __restrict__ b2,
                            float* __restrict__ out, int n, int nstride)
{
    float* As = (float*)smem;               // [32][132]
    float* Bs = (float*)(smem + 16896);     // [32][64]
    const u32* zw = (const u32*)zb;
    const int nsw = nstride >> 1;           // u32 stride per plane
    const int t  = threadIdx.x;
    const int tx = t & 15;
    const int ty = t >> 4;
    const int c  = t & 15;
    const int g  = t >> 4;
    const int ntiles = (n + 127) >> 7;
    for (int tile = blockIdx.x; tile < ntiles; tile += CGRID) {
        const int block_row = tile << 7;
        float acc[8][4];
        #pragma unroll
        for (int i = 0; i < 8; ++i)
            #pragma unroll
            for (int j = 0; j < 4; ++j) acc[i][j] = 0.f;

        for (int cc = 0; cc < 2; ++cc) {     // chunk = 2 hops = 32 cols
            #pragma unroll
            for (int i = 0; i < 8; ++i) {
                int row  = g + 16 * i;
                int grow = block_row + row;
                int pr     = c & 7;          // bf16-pair index within plane
                int pl_off = c >> 3;         // 0 or 1 within chunk
                int plane  = 6 + 2 * (cc * 2 + pl_off);   // 6,8,10,12 = H,G1,G2,G3
                float lo = 0.f, hi = 0.f;
                if (grow < n) {
                    u32 w = zw[(size_t)plane * nsw + (size_t)grow * 8 + pr];
                    lo = lo16f(w); hi = hi16f(w);
                }
                int col = pl_off * 16 + 2 * pr;
                As[(col + 0) * 132 + row] = lo;
                As[(col + 1) * 132 + row] = hi;
            }
            #pragma unroll
            for (int i2 = 0; i2 < 2; ++i2) {
                int kk = g + 16 * i2;
                int kglob = cc * 32 + kk;
                float4 wv = *(const float4*)(W2 + kglob * 64 + 4 * c);
                *(float4*)(Bs + kk * 64 + 4 * c) = wv;
            }
            __syncthreads();
            #pragma unroll 4
            for (int kk = 0; kk < 32; ++kk) {
                float4 a0 = *(const float4*)(As + kk * 132 + 8 * ty);
                float4 a1 = *(const float4*)(As + kk * 132 + 8 * ty + 4);
                float4 bv = *(const float4*)(Bs + kk * 64 + 4 * tx);
                float ar[8] = {a0.x, a0.y, a0.z, a0.w, a1.x, a1.y, a1.z, a1.w};
                float br[4] = {bv.x, bv.y, bv.z, bv.w};
                #pragma unroll
                for (int i = 0; i < 8; ++i)
                    #pragma unroll
                    for (int j = 0; j < 4; ++j)
                        acc[i][j] += ar[i] * br[j];
            }
            __syncthreads();
        }
        float4 bias = *(const float4*)(b2 + 4 * tx);
        #pragma unroll
        for (int i = 0; i < 8; ++i) {
            int grow = block_row + 8 * ty + i;
            if (grow < n) {
                float4 o = make_float4(acc[i][0] + bias.x, acc[i][1] + bias.y,
                                       acc[i][2] + bias.z, acc[i][3] + bias.w);
                *(float4*)(out + (long)grow * 64 + 4 * tx) = o;   // flushed at kernel end
            }
        }
        __syncthreads();
    }
}

// Single-assignment plane plan (each plane written in ONE phase, read only in
// LATER phases; never rewritten -> no stale clean lines anywhere):
//  0..3 = Z0..Z3 (gemm1)  4 = Y2 (hop1)  5 = Y1 (hop2)
//  6 = H, 7 = HT (hop3)   8 = G1, 9 = GT1 (hop4)
// 10 = G2, 11 = GT2 (hop5) 12 = G3 (hop6)
__global__ __launch_bounds__(256, 6) void compute_kernel(
    const float* __restrict__ x,
    const float* __restrict__ W1, const float* __restrict__ b1,
    const float* __restrict__ W2, const float* __restrict__ b2,
    float* __restrict__ out,
    int* barr, const int* __restrict__ rowptr, const u32* __restrict__ ecol,
    const float* __restrict__ dis, u16* zb, int n, int nstride)
{
    __shared__ __align__(16) char smem[CLDS];
    const int P = nstride;

    gemm1_phase(smem, x, W1, dis, zb, n, nstride);
    grid_bar(barr, 1);

    u16 *Z0 = zb,          *Z1 = zb + P,      *Z2 = zb + 2 * P,
        *Z3 = zb + 3 * P,  *Y2 = zb + 4 * P,  *Y1 = zb + 5 * P,
        *H  = zb + 6 * P,  *HT = zb + 7 * P,  *G1 = zb + 8 * P,
        *GT1 = zb + 9 * P, *G2 = zb + 10 * P, *GT2 = zb + 11 * P,
        *G3 = zb + 12 * P;

    // L1 Horner (tilde space: scale1 = dis^2)
    spmm_phase(smem, Z3, Z2, Y2, nullptr, rowptr, ecol, dis, nullptr, 0, 1, n);
    grid_bar(barr, 2);
    spmm_phase(smem, Y2, Z1, Y1, nullptr, rowptr, ecol, dis, nullptr, 0, 1, n);
    grid_bar(barr, 3);
    // H = relu(Z0 + dis*S + b1); HT = dis*H
    spmm_phase(smem, Y1, Z0, H, HT, rowptr, ecol, dis, b1, 1, 0, n);
    grid_bar(barr, 4);
    // L2 hops: Gk = dis*S, tilde copy GTk = dis*Gk
    spmm_phase(smem, HT, nullptr, G1, GT1, rowptr, ecol, dis, nullptr, 0, 0, n);
    grid_bar(barr, 5);
    spmm_phase(smem, GT1, nullptr, G2, GT2, rowptr, ecol, dis, nullptr, 0, 0, n);
    grid_bar(barr, 6);
    spmm_phase(smem, GT2, nullptr, G3, nullptr, rowptr, ecol, dis, nullptr, 0, 0, n);
    grid_bar(barr, 7);

    gemm2_phase(smem, zb, W2, b2, out, n, nstride);
}

// ================= fp32 fallback path (small workspace) =================
__global__ void deg_kernel(const int* __restrict__ dst, float* __restrict__ deg, int E) {
    int e = blockIdx.x * blockDim.x + threadIdx.x;
    if (e < E) atomicAdd(&deg[dst[e]], 1.0f);
}
__global__ void disf_kernel(float* __restrict__ deg, int n) {
    int i = blockIdx.x * blockDim.x + threadIdx.x;
    if (i < n) {
        float d = deg[i];
        deg[i] = (d > 0.0f) ? rsqrtf(d) : 0.0f;
    }
}
__global__ __launch_bounds__(256) void gemm1_f32_kernel(
    const float* __restrict__ x, const float* __restrict__ W1,
    float* __restrict__ z, int n, int nstride)
{
    __shared__ float As[64 * 132];
    __shared__ float Bs[64 * 64];
    __shared__ float sums[128];
    const int t  = threadIdx.x;
    const int tx = t & 15;
    const int ty = t >> 4;
    const int c  = t & 15;
    const int g  = t >> 4;
    const int block_row = blockIdx.x * 128;
    float acc[8][4];
    #pragma unroll
    for (int i = 0; i < 8; ++i)
        #pragma unroll
        for (int j = 0; j < 4; ++j) acc[i][j] = 0.f;
    for (int kp = 0; kp < 2; ++kp) {
        #pragma unroll
        for (int i = 0; i < 8; ++i) {
            int row  = g + 16 * i;
            int grow = block_row + row;
            float v0 = 0.f, v1 = 0.f, v2 = 0.f, v3 = 0.f;
            if (grow < n) {
                const float* xp = x + (long)grow * 128 + kp * 64 + c;
                v0 = xp[0]; v1 = xp[16]; v2 = xp[32]; v3 = xp[48];
            }
            As[(c +  0) * 132 + row] = v0;
            As[(c + 16) * 132 + row] = v1;
            As[(c + 32) * 132 + row] = v2;
            As[(c + 48) * 132 + row] = v3;
            float red = (v0 + v1) + (v2 + v3);
            #pragma unroll
            for (int off = 8; off > 0; off >>= 1) red += __shfl_down(red, off, 16);
            if (c == 0) { if (kp == 0) sums[row] = red; else sums[row] += red; }
        }
        #pragma unroll
        for (int i2 = 0; i2 < 4; ++i2) {
            int kk = g + 16 * i2;
            int kglob = kp * 64 + kk;
            float4 wv = *(const float4*)(W1 + (c >> 2) * 2048 + kglob * 16 + 4 * (c & 3));
            *(float4*)(Bs + kk * 64 + 4 * c) = wv;
        }
        __syncthreads();
        #pragma unroll 4
        for (int kk = 0; kk < 64; ++kk) {
            float4 a0 = *(const float4*)(As + kk * 132 + 8 * ty);
            float4 a1 = *(const float4*)(As + kk * 132 + 8 * ty + 4);
            float4 bv = *(const float4*)(Bs + kk * 64 + 4 * tx);
            float ar[8] = {a0.x, a0.y, a0.z, a0.w, a1.x, a1.y, a1.z, a1.w};
            float br[4] = {bv.x, bv.y, bv.z, bv.w};
            #pragma unroll
            for (int i = 0; i < 8; ++i)
                #pragma unroll
                for (int j = 0; j < 4; ++j)
                    acc[i][j] += ar[i] * br[j];
        }
        __syncthreads();
    }
    int plane = tx >> 2;
    int oo4   = 4 * (tx & 3);
    #pragma unroll
    for (int i = 0; i < 8; ++i) {
        int row  = 8 * ty + i;
        int grow = block_row + row;
        if (grow < n) {
            float s = 1.0f / fmaxf(sums[row], 1e-8f);
            float4 o = make_float4(acc[i][0] * s, acc[i][1] * s, acc[i][2] * s, acc[i][3] * s);
            *(float4*)(z + (long)plane * nstride + (long)grow * 16 + oo4) = o;
        }
    }
}
__global__ __launch_bounds__(256) void spmm_atomic_kernel(
    const float* __restrict__ in, float* __restrict__ out,
    const int* __restrict__ src, const int* __restrict__ dst,
    const float* __restrict__ dis, int E)
{
    int t = blockIdx.x * blockDim.x + threadIdx.x;
    int e = t >> 4, f = t & 15;
    if (e < E) {
        int s = src[e], d = dst[e];
        atomicAdd(&out[d * 16 + f], dis[s] * dis[d] * in[s * 16 + f]);
    }
}
__global__ void bias_relu_kernel(float* __restrict__ z0, const float* __restrict__ b, int total) {
    int i = blockIdx.x * blockDim.x + threadIdx.x;
    if (i < total) {
        float v = z0[i] + b[i & 15];
        z0[i] = v > 0.0f ? v : 0.0f;
    }
}
__global__ __launch_bounds__(256) void gemm2_f32_kernel(
    const float* __restrict__ z, const float* __restrict__ W2,
    const float* __restrict__ b2, float* __restrict__ out, int n, int nstride)
{
    __shared__ float As[64 * 132];
    __shared__ float Bs[64 * 64];
    const int t  = threadIdx.x;
    const int tx = t & 15;
    const int ty = t >> 4;
    const int c  = t & 15;
    const int g  = t >> 4;
    const int block_row = blockIdx.x * 128;
    float acc[8][4];
    #pragma unroll
    for (int i = 0; i < 8; ++i)
        #pragma unroll
        for (int j = 0; j < 4; ++j) acc[i][j] = 0.f;
    #pragma unroll
    for (int i = 0; i < 8; ++i) {
        int row  = g + 16 * i;
        int grow = block_row + row;
        float v0 = 0.f, v1 = 0.f, v2 = 0.f, v3 = 0.f;
        if (grow < n) {
            const float* zp = z + (long)grow * 16 + c;
            v0 = zp[0];
            v1 = zp[(long)nstride];
            v2 = zp[2 * (long)nstride];
            v3 = zp[3 * (long)nstride];
        }
        As[(c +  0) * 132 + row] = v0;
        As[(c + 16) * 132 + row] = v1;
        As[(c + 32) * 132 + row] = v2;
        As[(c + 48) * 132 + row] = v3;
    }
    #pragma unroll
    for (int i2 = 0; i2 < 4; ++i2) {
        int j = g + 16 * i2;
        float4 wv = *(const float4*)(W2 + j * 64 + 4 * c);
        *(float4*)(Bs + j * 64 + 4 * c) = wv;
    }
    __syncthreads();
    #pragma unroll 4
    for (int kk = 0; kk < 64; ++kk) {
        float4 a0 = *(const float4*)(As + kk * 132 + 8 * ty);
        float4 a1 = *(const float4*)(As + kk * 132 + 8 * ty + 4);
        float4 bv = *(const float4*)(Bs + kk * 64 + 4 * tx);
        float ar[8] = {a0.x, a0.y, a0.z, a0.w, a1.x, a1.y, a1.z, a1.w};
        float br[4] = {bv.x, bv.y, bv.z, bv.w};
        #pragma unroll
        for (int i = 0; i < 8; ++i)
            #pragma unroll
            for (int j = 0; j < 4; ++j)
                acc[i][j] += ar[i] * br[j];
    }
    float4 bias = *(const float4*)(b2 + 4 * tx);
    #pragma unroll
    for (int i = 0; i < 8; ++i) {
        int grow = block_row + 8 * ty + i;
        if (grow < n) {
            float4 o = make_float4(acc[i][0] + bias.x, acc[i][1] + bias.y,
                                   acc[i][2] + bias.z, acc[i][3] + bias.w);
            *(float4*)(out + (long)grow * 64 + 4 * tx) = o;
        }
    }
}

static inline size_t align16(size_t v) { return (v + 15) & ~(size_t)15; }

extern "C" void kernel_launch(void* const* d_in, const int* in_sizes, int n_in,
                              void* d_out, int out_size, void* d_ws, size_t ws_size,
                              hipStream_t stream) {
    const float* x   = (const float*)d_in[0];
    const int*   ei  = (const int*)d_in[1];
    const float* W1  = (const float*)d_in[2];
    const float* b1  = (const float*)d_in[3];
    const float* W2  = (const float*)d_in[4];
    const float* bb2 = (const float*)d_in[5];
    float* out = (float*)d_out;

    const int n  = in_sizes[0] / 128;   // 50000
    const int E  = in_sizes[1] / 2;     // 800000
    const int NS = n * 16;

    const int* srcp = ei;
    const int* dstp = ei + E;

    const int nbuck = (n + BKT_SIZE - 1) >> BKT_SHIFT;
    const int nbA   = (E + CHUNK - 1) / CHUNK;
    const int m     = nbuck * nbA;
    const int nbS   = (m + 255) / 256;

    char* wsb = (char*)d_ws;
    // layout: barr(4096) | hist[m] | hofs[m+1] | bsum[1024] | rowptr[n+1] | dis[n]
    //         | ecol[E u32] | union( bucketed[E int2] , zb[13*NS u16] )
    // bucketed is build-only; zb is compute-only -> alias them.
    int*   barr   = (int*)wsb;
    int*   hist   = (int*)(wsb + 4096);
    int*   hofs   = (int*)(wsb + 4096 + (size_t)4 * m);
    int*   bsum   = (int*)(wsb + 4096 + (size_t)4 * (2 * m + 1));
    int*   rowptr = (int*)(wsb + 4096 + (size_t)4 * (2 * m + 1 + 1024));
    float* dis    = (float*)(wsb + 4096 + (size_t)4 * (2 * m + 1 + 1024 + n + 1));
    size_t ecooff = align16(4096 + (size_t)4 * (2 * m + 1 + 1024 + 2 * n + 1));
    u32*   ecol   = (u32*)(wsb + ecooff);
    size_t bigoff = align16(ecooff + (size_t)4 * E);
    int2*  bucketed = (int2*)(wsb + bigoff);
    u16*   zb     = (u16*)(wsb + bigoff);
    size_t bigsz  = (size_t)8 * E;
    size_t zbsz   = (size_t)2 * 13 * NS;
    size_t need   = bigoff + (bigsz > zbsz ? bigsz : zbsz);

    if (ws_size >= need && nbuck <= 512 && nbS <= 1024) {
        hipMemsetAsync(barr, 0, 4096, stream);
        // ---- proven multi-kernel CSR build (zero global atomics) ----
        hist_kernel<<<nbA, 256, 0, stream>>>(dstp, hist, E, nbA, nbuck);
        scanA_kernel<<<nbS, 256, 0, stream>>>(hist, hofs, bsum, m);
        scanB_kernel<<<1, 1024, 0, stream>>>(bsum, nbS);
        scanC_kernel<<<nbS, 256, 0, stream>>>(hofs, bsum, m);
        bucket_scatter_kernel<<<nbA, 256, 0, stream>>>(srcp, dstp, hofs, bucketed, E, nbA, nbuck);
        csr_finalize_kernel<<<nbuck, 256, 0, stream>>>(bucketed, hofs, rowptr, dis, ecol, E, nbA, nbuck, n);
        // ---- persistent compute (cached stores + per-XCD wbl2 barriers) ----
        compute_kernel<<<CGRID, 256, 0, stream>>>(
            x, W1, b1, W2, bb2, out, barr, rowptr, ecol, dis, zb, n, NS);
    } else {
        // ---------- fp32 atomic fallback ----------
        int gemm_blocks = (n + 127) / 128;
        float* ws = (float*)d_ws;
        float* dis2 = ws;
        size_t z2off = ((size_t)n + 3) & ~(size_t)3;
        float* z2 = ws + z2off;
        hipMemsetAsync(dis2, 0, n * sizeof(float), stream);
        deg_kernel<<<(E + 255) / 256, 256, 0, stream>>>(dstp, dis2, E);
        disf_kernel<<<(n + 255) / 256, 256, 0, stream>>>(dis2, n);
        gemm1_f32_kernel<<<gemm_blocks, 256, 0, stream>>>(x, W1, z2, n, NS);
        int sb = (16 * E + 255) / 256;
        spmm_atomic_kernel<<<sb, 256, 0, stream>>>(z2 + 3 * NS, z2 + 2 * NS, srcp, dstp, dis2, E);
        spmm_atomic_kernel<<<sb, 256, 0, stream>>>(z2 + 2 * NS, z2 + 1 * NS, srcp, dstp, dis2, E);
        spmm_atomic_kernel<<<sb, 256, 0, stream>>>(z2 + 1 * NS, z2,          srcp, dstp, dis2, E);
        bias_relu_kernel<<<(NS + 255) / 256, 256, 0, stream>>>(z2, b1, NS);
        hipMemsetAsync(z2 + NS, 0, (size_t)3 * NS * sizeof(float), stream);
        spmm_atomic_kernel<<<sb, 256, 0, stream>>>(z2,          z2 + NS,     srcp, dstp, dis2, E);
        spmm_atomic_kernel<<<sb, 256, 0, stream>>>(z2 + NS,     z2 + 2 * NS, srcp, dstp, dis2, E);
        spmm_atomic_kernel<<<sb, 256, 0, stream>>>(z2 + 2 * NS, z2 + 3 * NS, srcp, dstp, dis2, E);
        gemm2_f32_kernel<<<gemm_blocks, 256, 0, stream>>>(z2, W2, bb2, out, n, NS);
    }
}